// Round 11
// baseline (332.526 us; speedup 1.0000x reference)
//
#include <hip/hip_runtime.h>

// Problem: B,C,H,W = 16,256,32,32; K=16384. N = 16384 rows.
// R21: R10 post-mortem: k2 at 217us, VALUBusy 31% > MfmaUtil 27.6% -> VALU is
//      the top pipe. Cuts (structure frozen from R10): (1) unconditional B
//      prefetch -- the one-past-end load (ch15/cs7) reads the wn region of the
//      workspace (valid memory, never consumed), deleting the guard branch and
//      else-copies; (2) manual 2-phase cs unroll with named b0/b1 register sets
//      -- kills the 16 v_mov/step cur=nxt rotation by construction; (3) single
//      running B pointer (nps += 8192/step; swizzled layout is linear in
//      s = ch*8+cs, so it crosses ch boundaries with one add).
//      Spill tripwire: WRITE_SIZE >50MB = spill (R7 signature); b0+b1(32) +
//      acc(64 AGPR) + addr ~= 110 unified < 128 cap.
#define KCODES 16384
#define NPOS   16384
#define KQUART 4096
#define CAPH   32      // per-quarter candidate cap (R5-proven at this dv-window)
#define MARGIN 1e-4f   // dv-space margin; acc-space threshold uses MARGIN/2

// ws float offsets (all within the 52.7MB footprint proven in R0)
#define OFF_XT    0           // [N][256] fp32 packed x ("flat")
#define OFF_XHP   4194304     // bf16 plane xh [N][256] (linear)
#define OFF_PART  6291456     // [4096][2] k3 per-wave {mask,err} partials
#define OFF_CAND  6815744     // u16 [N][4][CAPH=32] candidate codes (1M floats)
#define OFF_WHP   8388608     // bf16 plane wh, SWIZZLED [quarter][s][w][ct][nn][q][8]
#define OFF_WN    12582912    // [K]  |w|^2 (np-pairwise exact; also absorbs the
                              //      harmless one-past-end prefetch of whp)
#define OFF_NS1   12599296    // [N] -|f|^2
#define OFF_IDX   12615680    // [N] final argmax (int)
#define OFF_CCNT  12632064    // int [N][4] candidate counts (ends 12697600)
#define OFF_QMAX  12697600    // fp32 [N][4] per-quarter approx ACC-max (ends 12763136)

#define OUT_LOSS  4194304
#define OUT_IND   4194305

#define AS1 __attribute__((address_space(1)))
#define AS3 __attribute__((address_space(3)))

typedef short bf16x8 __attribute__((ext_vector_type(8)));   // 8 bf16 = 4 VGPRs
typedef float f32x4  __attribute__((ext_vector_type(4)));

__device__ inline unsigned short bf16rn(float f) {
    unsigned u = __float_as_uint(f);
    return (unsigned short)((u + 0x7FFFu + ((u >> 16) & 1u)) >> 16);
}
__device__ inline float bf2f(unsigned short h) {
    return __uint_as_float(((unsigned)h) << 16);
}
__device__ inline unsigned monof(float f) {   // monotone float->uint key
    unsigned u = __float_as_uint(f);
    return (u & 0x80000000u) ? ~u : (u | 0x80000000u);
}
__device__ inline float unmonof(unsigned k) {
    unsigned u = (k & 0x80000000u) ? (k & 0x7fffffffu) : ~k;
    return __uint_as_float(u);
}

// ---------- K1a: pack x (B,C,HW) -> xt[N][256] fp32 + xh bf16, LDS transpose ----
__global__ void k1a_pack_x(const float* __restrict__ x, float* __restrict__ xt,
                           unsigned short* __restrict__ xhp)
{
    __shared__ float t[32][33];
    const int p0 = blockIdx.x * 32, c0 = blockIdx.y * 32, b = blockIdx.z;
    const int tx = threadIdx.x, ty = threadIdx.y;   // 32 x 8
#pragma unroll
    for (int i = 0; i < 4; ++i) {
        int cl = ty + i * 8;
        t[cl][tx] = x[(b * 256 + c0 + cl) * 1024 + p0 + tx];
    }
    __syncthreads();
#pragma unroll
    for (int i = 0; i < 4; ++i) {
        int pl = ty + i * 8;
        float v = t[tx][pl];
        int o = (b * 1024 + p0 + pl) * 256 + c0 + tx;
        xt[o] = v;
        xhp[o] = bf16rn(v);
    }
}

// ---------- Krn: numpy-pairwise fp32 row |.|^2; weight path also emits the ------
// ---------- SWIZZLED bf16 plane in k2's fragment order -------------------------
// swizzle: code k -> (qt = k>>12; chi = (k&4095)>>8; rem = k&255 -> w,ct,nn),
// channel c (as float4 idx c4 = c/4) -> (cs = c4>>3; q = (c4>>1)&3; e4 = c4&1).
// short idx = qt*1048576 + (chi*8+cs)*8192 + w*2048 + ct*512 + nn*32 + q*8 + e4*4.
__global__ void k_rownorm(const float4* __restrict__ src4, float* __restrict__ out,
                          float sign, unsigned short* __restrict__ hp_swz)
{
    __shared__ float4 rows[32 * 64];
    const int tid = threadIdx.x;
    const int r0 = blockIdx.x * 32;
#pragma unroll
    for (int i = 0; i < 8; ++i) {
        const int F = r0 * 64 + tid + 256 * i;    // float4 index: row = F>>6, c4 = F&63
        const float4 v = src4[F];
        rows[tid + 256 * i] = v;
        if (hp_swz) {
            ushort4 h;
            h.x = bf16rn(v.x); h.y = bf16rn(v.y);
            h.z = bf16rn(v.z); h.w = bf16rn(v.w);
            const int row = F >> 6, c4 = F & 63;
            const int qt = row >> 12, kk = row & 4095;
            const int chi = kk >> 8, rem = kk & 255;
            const int wq = rem >> 6, ct = (rem >> 4) & 3, n4 = rem & 15;
            const int cs = c4 >> 3, qq = (c4 >> 1) & 3, e4 = c4 & 1;
            const int sidx = qt * 1048576 + (chi * 8 + cs) * 8192
                           + wq * 2048 + ct * 512 + n4 * 32 + qq * 8 + e4 * 4;
            *(ushort4*)(hp_swz + sidx) = h;
        }
    }
    __syncthreads();
    const int rl = tid >> 3, j = tid & 7;
    const float* qp = (const float*)&rows[rl * 64];
    float h[2];
#pragma unroll
    for (int half = 0; half < 2; ++half) {
        const float* p = qp + half * 128;
        float x = p[j];
        float r = __fmul_rn(x, x);
#pragma unroll
        for (int i = 1; i < 16; ++i) {
            float y = p[8 * i + j];
            r = __fadd_rn(r, __fmul_rn(y, y));
        }
        float t = __fadd_rn(r, __shfl_xor(r, 1));
        t = __fadd_rn(t, __shfl_xor(t, 2));
        t = __fadd_rn(t, __shfl_xor(t, 4));
        h[half] = t;
    }
    if (j == 0) out[r0 + rl] = sign * __fadd_rn(h[0], h[1]);
}

// ---------- K2: 64-row x K-quarter, direct-to-reg B, raw-acc fold --------------
// Selection on raw acc (= xh.wh dot): th = rowAccMax - MARGIN/2. The -|w|^2 and
// -|f|^2 terms are omitted (|w|^2 <= 9.5e-7 << MARGIN; -|f|^2 row-constant).
// Block = (rowGroup = bid>>2) x (quarter = bid&3). 1024 blocks = 4/CU.
__global__ __launch_bounds__(256, 4) void k2_mfma(
    const unsigned short* __restrict__ xhp, const unsigned short* __restrict__ whp,
    unsigned short* __restrict__ candk, int* __restrict__ candc,
    float* __restrict__ qmax)
{
    __shared__ __align__(16) unsigned short As[16384];     // 32KB: slot16 = cc*64 + row
    __shared__ unsigned rowmaxU[64];                       // block-shared monotone max
    __shared__ int ccnt[64];
    __shared__ unsigned short ck[64][CAPH];                // 4 KB

    const int tid  = threadIdx.x;
    const int lane = tid & 63;
    const int w    = tid >> 6;     // wave 0..3 -> code sub-range
    const int q    = lane >> 4;    // k-chunk quad
    const int nn   = lane & 15;    // A-row / B-col / D-col position
    const int qt   = blockIdx.x & 3;
    const int rowBase = (blockIdx.x >> 2) * 64;
    const unsigned short* whpQ = whp + qt * 1048576;

    // stage A once: 1024 slots of 16B (64 rows x 256 ch bf16), linear dest
#pragma unroll
    for (int i = 0; i < 8; ++i) {
        const int slot = i * 256 + tid;
        const int cc = slot >> 6, row = slot & 63;
        const unsigned short* src = xhp + (rowBase + row) * 256 + cc * 8;
        __builtin_amdgcn_global_load_lds((const AS1 void*)src,
                                         (AS3 void*)((char*)&As[0] + slot * 16), 16, 0, 0);
    }
    if (tid < 64) { rowmaxU[tid] = 0u; ccnt[tid] = 0; }

    // per-lane fragment pointer into the swizzled codebook quarter
    const unsigned short* bptr = whpQ + (w * 2048 + nn * 32 + q * 8);

    __syncthreads();           // As staged (drains vmcnt once)

    // 2-phase register pipeline: b0 holds step s (even), b1 step s+1 (odd).
    // nps is the single running prefetch pointer, linear in s across ch.
    bf16x8 b0[4], b1[4];
#pragma unroll
    for (int ct = 0; ct < 4; ++ct)
        b0[ct] = *(const bf16x8*)(bptr + ct * 512);        // step 0
    const unsigned short* nps = bptr + 8192;               // next prefetch = step 1

    for (int ch = 0; ch < 16; ++ch) {
        const int kb = ch * 256;
        f32x4 acc[4][4];
#pragma unroll
        for (int rt = 0; rt < 4; ++rt)
#pragma unroll
            for (int ct = 0; ct < 4; ++ct) acc[rt][ct] = (f32x4){0.f, 0.f, 0.f, 0.f};

#pragma unroll
        for (int cs2 = 0; cs2 < 4; ++cs2) {
            // EVEN step (cs = 2*cs2): prefetch s+1 into b1, compute from b0.
            // (one-past-end prefetches land in the wn region: valid, unused)
#pragma unroll
            for (int ct = 0; ct < 4; ++ct)
                b1[ct] = *(const bf16x8*)(nps + ct * 512);
            nps += 8192;
#pragma unroll
            for (int rt = 0; rt < 4; ++rt) {
                const int as = ((2 * cs2) * 4 + q) * 64 + rt * 16 + nn;
                const bf16x8 ah = *(const bf16x8*)&As[as * 8];
#pragma unroll
                for (int ct = 0; ct < 4; ++ct)
                    acc[rt][ct] = __builtin_amdgcn_mfma_f32_16x16x32_bf16(ah, b0[ct], acc[rt][ct], 0, 0, 0);
            }
            // ODD step (cs = 2*cs2+1): prefetch s+2 into b0, compute from b1.
#pragma unroll
            for (int ct = 0; ct < 4; ++ct)
                b0[ct] = *(const bf16x8*)(nps + ct * 512);
            nps += 8192;
#pragma unroll
            for (int rt = 0; rt < 4; ++rt) {
                const int as = ((2 * cs2 + 1) * 4 + q) * 64 + rt * 16 + nn;
                const bf16x8 ah = *(const bf16x8*)&As[as * 8];
#pragma unroll
                for (int ct = 0; ct < 4; ++ct)
                    acc[rt][ct] = __builtin_amdgcn_mfma_f32_16x16x32_bf16(ah, b1[ct], acc[rt][ct], 0, 0, 0);
            }
        }

        // ---- fold on RAW acc: max -> atomicMax -> barrier -> collect ----
#pragma unroll
        for (int rt = 0; rt < 4; ++rt)
#pragma unroll
            for (int rg = 0; rg < 4; ++rg) {
                float m = fmaxf(fmaxf(acc[rt][0][rg], acc[rt][1][rg]),
                                fmaxf(acc[rt][2][rg], acc[rt][3][rg]));
                m = fmaxf(m, __shfl_xor(m, 1, 64));
                m = fmaxf(m, __shfl_xor(m, 2, 64));
                m = fmaxf(m, __shfl_xor(m, 4, 64));
                m = fmaxf(m, __shfl_xor(m, 8, 64));
                if (nn == 0)
                    atomicMax(&rowmaxU[rt * 16 + q * 4 + rg], monof(m));
            }
        __syncthreads();       // rowmax merged across waves (tight threshold)
#pragma unroll
        for (int rt = 0; rt < 4; ++rt)
#pragma unroll
            for (int rg = 0; rg < 4; ++rg) {
                const int row = rt * 16 + q * 4 + rg;
                const float th = unmonof(rowmaxU[row]) - (0.5f * MARGIN);
#pragma unroll
                for (int ct = 0; ct < 4; ++ct)
                    if (acc[rt][ct][rg] >= th) {
                        const int pos = atomicAdd(&ccnt[row], 1);
                        if (pos < CAPH)
                            ck[row][pos] = (unsigned short)(qt * KQUART + kb + w * 64 + ct * 16 + nn);
                    }
            }
        // no trailing barrier: a fast wave's ch+1 atomicMax only RAISES rowmaxU,
        // which keeps th <= trueQuarterAccMax; headroom >= 10x keeps the argmax.
    }
    __syncthreads();           // all waves' collections visible
    if (tid < 64) {
        candc[(rowBase + tid) * 4 + qt] = ccnt[tid];
        qmax[(rowBase + tid) * 4 + qt] = unmonof(rowmaxU[tid]);
    }
#pragma unroll
    for (int i = 0; i < 8; ++i) {
        const int e = i * 256 + tid;    // 2048 entries = 64 rows x CAPH(32)
        candk[((rowBase + (e >> 5)) * 4 + qt) * CAPH + (e & 31)] = ck[e >> 5][e & 31];
    }
}

// ---------- K3: exact rescore w/ quarter-skip + fused loss partials ------------
__global__ __launch_bounds__(256) void k3_rescore(
    const float* __restrict__ xt, const float* __restrict__ weight,
    const float* __restrict__ wn, const float* __restrict__ ns1,
    const float* __restrict__ qmax,
    const unsigned short* __restrict__ candk, const int* __restrict__ candc,
    const float* __restrict__ mask,
    int* __restrict__ idx, float* __restrict__ out, float* __restrict__ part)
{
    const int w = threadIdx.x >> 6, lane = threadIdx.x & 63;
    const int waveId = blockIdx.x * 4 + w;        // 0..4095
    float mm = 0.f, merr = 0.f;
#pragma unroll
    for (int rr = 0; rr < 4; ++rr) {
        const int n = waveId * 4 + rr;
        const float4 xv = ((const float4*)(xt + n * 256))[lane];
        const float nsv = ns1[n];
        const float4 qm = ((const float4*)(qmax + n * 4))[0];
        // acc-space skip: quarter can't hold the argmax if its acc-max is more
        // than MARGIN/2 below the global acc-max (same headroom proof as k2).
        const float qth = fmaxf(fmaxf(qm.x, qm.y), fmaxf(qm.z, qm.w)) - (0.5f * MARGIN);
        float bestd = -3.0e38f; int bestk = 0x7fffffff;
#pragma unroll
        for (int qt = 0; qt < 4; ++qt) {
            const float qv = (qt == 0) ? qm.x : (qt == 1) ? qm.y : (qt == 2) ? qm.z : qm.w;
            if (qv < qth) continue;               // quarter can't hold the argmax
            const int cnt = candc[n * 4 + qt];
            if (cnt <= CAPH) {
                for (int i = 0; i < cnt; ++i) {
                    const int k = candk[(n * 4 + qt) * CAPH + i];
                    const float4 wv = ((const float4*)(weight + k * 256))[lane];
                    float p = __fmul_rn(xv.x, wv.x);
                    p = __builtin_fmaf(xv.y, wv.y, p);
                    p = __builtin_fmaf(xv.z, wv.z, p);
                    p = __builtin_fmaf(xv.w, wv.w, p);
#pragma unroll
                    for (int off = 1; off < 64; off <<= 1) p += __shfl_xor(p, off, 64);
                    const float t1 = __fadd_rn(nsv, -wn[k]);
                    const float dd = __fadd_rn(t1, __fmul_rn(2.0f, p));
                    if (dd > bestd || (dd == bestd && k < bestk)) { bestd = dd; bestk = k; }
                }
            } else {          // overflow fallback: exact scan of this quarter
                for (int k = qt * KQUART; k < (qt + 1) * KQUART; ++k) {
                    const float4 wv = ((const float4*)(weight + k * 256))[lane];
                    float p = __fmul_rn(xv.x, wv.x);
                    p = __builtin_fmaf(xv.y, wv.y, p);
                    p = __builtin_fmaf(xv.z, wv.z, p);
                    p = __builtin_fmaf(xv.w, wv.w, p);
#pragma unroll
                    for (int off = 1; off < 64; off <<= 1) p += __shfl_xor(p, off, 64);
                    const float t1 = __fadd_rn(nsv, -wn[k]);
                    const float dd = __fadd_rn(t1, __fmul_rn(2.0f, p));
                    if (dd > bestd || (dd == bestd && k < bestk)) { bestd = dd; bestk = k; }
                }
            }
        }
        if (lane == 0) { idx[n] = bestk; out[OUT_IND + n] = (float)bestk; }
        // fused masked loss: winner row is L2-hot (just scanned)
        const float4 wv = ((const float4*)(weight + bestk * 256))[lane];
        float ex = wv.x - xv.x, ey = wv.y - xv.y, ez = wv.z - xv.z, ew = wv.w - xv.w;
        float s = ex * ex + ey * ey + ez * ez + ew * ew;
#pragma unroll
        for (int off = 1; off < 64; off <<= 1) s += __shfl_xor(s, off, 64);
        const float mval = mask[n];
        mm += mval; merr += mval * s;
    }
    if (lane == 0) { part[waveId * 2 + 0] = mm; part[waveId * 2 + 1] = merr; }
}

// ---------- K5: pure gather + transpose-tile coalesced store ------------------
__global__ void k5_out(const float* __restrict__ weight, const int* __restrict__ idx,
                       float* __restrict__ out)
{
    __shared__ float t[32][33];
    const int p0 = blockIdx.x * 32, c0 = blockIdx.y * 32, b = blockIdx.z;
    const int tx = threadIdx.x, ty = threadIdx.y;
#pragma unroll
    for (int i = 0; i < 4; ++i) {
        const int pl = ty + i * 8;
        const int n = b * 1024 + p0 + pl;
        t[tx][pl] = weight[idx[n] * 256 + c0 + tx];       // coalesced 128B per row
    }
    __syncthreads();
#pragma unroll
    for (int i = 0; i < 4; ++i) {
        const int cl = ty + i * 8;
        out[(b * 256 + c0 + cl) * 1024 + p0 + tx] = t[cl][tx];   // coalesced in tx
    }
}

// ---------- K6: deterministic tree-reduce of 4096 partials + finalize loss ----
__global__ void k6_final(const float* __restrict__ part, float* __restrict__ out)
{
    __shared__ double red[4][2];
    const int tid = threadIdx.x;
    double m = 0.0, s = 0.0;
    for (int i = tid; i < 4096; i += 256) {
        m += (double)part[i * 2 + 0];
        s += (double)part[i * 2 + 1];
    }
    const int lane = tid & 63, w = tid >> 6;
    for (int o = 32; o > 0; o >>= 1) {
        m += __shfl_down(m, o, 64);
        s += __shfl_down(s, o, 64);
    }
    if (lane == 0) { red[w][0] = m; red[w][1] = s; }
    __syncthreads();
    if (tid == 0) {
        const double mt = red[0][0] + red[1][0] + red[2][0] + red[3][0];
        const double st = red[0][1] + red[1][1] + red[2][1] + red[3][1];
        out[OUT_LOSS] = (float)(1.25 * st / (256.0 * mt));
    }
}

extern "C" void kernel_launch(void* const* d_in, const int* in_sizes, int n_in,
                              void* d_out, int out_size, void* d_ws, size_t ws_size,
                              hipStream_t stream)
{
    const float* x      = (const float*)d_in[0];   // [16,256,32,32]
    const float* mask   = (const float*)d_in[1];   // [16,1,32,32]
    const float* weight = (const float*)d_in[2];   // [16384,256]
    float* out = (float*)d_out;
    float* ws  = (float*)d_ws;

    float* xt  = ws + OFF_XT;
    unsigned short* xhp = (unsigned short*)(ws + OFF_XHP);
    unsigned short* whp = (unsigned short*)(ws + OFF_WHP);
    float* wn   = ws + OFF_WN;
    float* ns1  = ws + OFF_NS1;
    int*   idx  = (int*)(ws + OFF_IDX);
    unsigned short* candk = (unsigned short*)(ws + OFF_CAND);
    int*   candc = (int*)(ws + OFF_CCNT);
    float* qmaxA = ws + OFF_QMAX;
    float* part = ws + OFF_PART;

    k1a_pack_x<<<dim3(32, 8, 16), dim3(32, 8), 0, stream>>>(x, xt, xhp);
    k_rownorm<<<512, 256, 0, stream>>>((const float4*)xt, ns1, -1.0f, nullptr);
    k_rownorm<<<512, 256, 0, stream>>>((const float4*)weight, wn, 1.0f, whp);
    k2_mfma<<<1024, 256, 0, stream>>>(xhp, whp, candk, candc, qmaxA);
    k3_rescore<<<1024, 256, 0, stream>>>(xt, weight, wn, ns1, qmaxA, candk, candc,
                                         mask, idx, out, part);
    k5_out<<<dim3(32, 8, 16), dim3(32, 8), 0, stream>>>(weight, idx, out);
    k6_final<<<1, 256, 0, stream>>>(part, out);
}